// Round 1
// baseline (290.978 us; speedup 1.0000x reference)
//
#include <hip/hip_runtime.h>
#include <hip/hip_bf16.h>
#include <cstdint>
#include <cstddef>

#define NTOK 32768
#define DIN 512
#define EDIM_ 256
#define HID 1024
#define NEXP 4
#define RK 768

typedef __attribute__((ext_vector_type(8))) short short8;
typedef __attribute__((ext_vector_type(4))) float f32x4;
typedef __attribute__((ext_vector_type(4))) unsigned short u16x4;

typedef __attribute__((address_space(1))) const void gv_t;
typedef __attribute__((address_space(3))) void lv_t;

// ---- workspace layout (bytes) ----
#define OFF_COUNTS 0
#define OFF_TILE   64
#define OFF_GIDX   256
#define OFF_GVAL   (OFF_GIDX + 131072)
#define OFF_PERM   (OFF_GVAL + 131072)
#define OFF_PART   (OFF_PERM + 524288)
#define OFF_WB1    (OFF_PART + 81920)
#define OFF_WB2    (OFF_WB1 + 4194304)
// total ~9.26 MB

__device__ __forceinline__ unsigned short f2bf(float f) {
  unsigned u = __float_as_uint(f);
  u = (u + 0x7fffu + ((u >> 16) & 1u)) >> 16;
  return (unsigned short)u;
}

__device__ __forceinline__ f32x4 mfma16(short8 a, short8 b, f32x4 c) {
  return __builtin_amdgcn_mfma_f32_16x16x32_bf16(a, b, c, 0, 0, 0);
}

// ---------------- weight convert f32 -> bf16 ----------------
__global__ __launch_bounds__(256) void cvt_kernel(const float4* __restrict__ w1,
                                                  const float4* __restrict__ w2,
                                                  unsigned short* __restrict__ wb1,
                                                  unsigned short* __restrict__ wb2) {
  const int i = blockIdx.x * 256 + threadIdx.x;  // 0..524287, covers 2097152 elems
  float4 a = w1[i];
  float4 b = w2[i];
  u16x4 pa, pb;
  pa[0] = f2bf(a.x); pa[1] = f2bf(a.y); pa[2] = f2bf(a.z); pa[3] = f2bf(a.w);
  pb[0] = f2bf(b.x); pb[1] = f2bf(b.y); pb[2] = f2bf(b.z); pb[3] = f2bf(b.w);
  *(u16x4*)(wb1 + (size_t)i * 4) = pa;
  *(u16x4*)(wb2 + (size_t)i * 4) = pb;
}

// ---------------- router: logits, softmax, gate, loss partials ----------------
__global__ __launch_bounds__(256) void router_kernel(const float* __restrict__ x,
                                                     const float* __restrict__ emb,
                                                     const float* __restrict__ rw,
                                                     int* __restrict__ gidx,
                                                     float* __restrict__ gval,
                                                     double* __restrict__ partials) {
  __shared__ float rws[RK * 4];
  __shared__ double vals[16][5];
  for (int i = threadIdx.x; i < RK * 4; i += 256) rws[i] = rw[i];
  __syncthreads();
  const int wave = threadIdx.x >> 6, lane = threadIdx.x & 63;
  for (int it = 0; it < 4; it++) {
    const int t = blockIdx.x * 16 + wave * 4 + it;
    double a0 = 0, a1 = 0, a2 = 0, a3 = 0;
    const float* er = emb + (size_t)t * EDIM_;
    const float* xr = x + (size_t)t * DIN;
    for (int j = lane; j < RK; j += 64) {
      float v = (j < EDIM_) ? er[j] : xr[j - EDIM_];
      const float* w = rws + j * 4;
      a0 += (double)v * w[0]; a1 += (double)v * w[1];
      a2 += (double)v * w[2]; a3 += (double)v * w[3];
    }
    for (int off = 32; off > 0; off >>= 1) {
      a0 += __shfl_down(a0, off); a1 += __shfl_down(a1, off);
      a2 += __shfl_down(a2, off); a3 += __shfl_down(a3, off);
    }
    if (lane == 0) {
      double l[4] = {a0, a1, a2, a3};
      int bi = 0; double mx = l[0];
      for (int k = 1; k < 4; k++) if (l[k] > mx) { mx = l[k]; bi = k; }
      double p[4], s = 0;
      for (int k = 0; k < 4; k++) { p[k] = exp(l[k] - mx); s += p[k]; }
      double inv = 1.0 / s, sq = 0, sp = 0;
      for (int k = 0; k < 4; k++) { p[k] *= inv; sq += p[k] * p[k]; sp += p[k]; }
      gidx[t] = bi;
      gval[t] = (float)p[bi];
      double* vv = vals[wave * 4 + it];
      vv[0] = p[0]; vv[1] = p[1]; vv[2] = p[2]; vv[3] = p[3];
      vv[4] = sp / (sqrt(sq) + 1e-10);
    }
  }
  __syncthreads();
  if (threadIdx.x < 5) {
    double acc = 0;
    for (int k = 0; k < 16; k++) acc += vals[k][threadIdx.x];
    partials[(size_t)blockIdx.x * 5 + threadIdx.x] = acc;
  }
}

// ---------------- scatter: build per-expert token lists ----------------
__global__ __launch_bounds__(256) void scatter_kernel(const int* __restrict__ gidx,
                                                      unsigned* __restrict__ counts,
                                                      unsigned* __restrict__ perm) {
  const int t = blockIdx.x * 256 + threadIdx.x;
  const int lane = threadIdx.x & 63;
  const int e = gidx[t];
  for (int ei = 0; ei < NEXP; ei++) {
    unsigned long long mask = __ballot(e == ei);
    if (mask == 0ull) continue;
    const int leader = __ffsll((unsigned long long)mask) - 1;
    unsigned base = 0;
    if (lane == leader) base = atomicAdd(&counts[ei], (unsigned)__popcll(mask));
    base = __shfl(base, leader, 64);
    if (e == ei) {
      const int rank = __popcll(mask & ((1ull << lane) - 1ull));
      perm[(size_t)ei * NTOK + base + rank] = (unsigned)t;
    }
  }
}

// ---------------- setup: losses + tile bases ----------------
__global__ __launch_bounds__(256) void setup_kernel(const unsigned* __restrict__ counts,
                                                    unsigned* __restrict__ tileinfo,
                                                    const double* __restrict__ partials,
                                                    float* __restrict__ scal) {
  __shared__ double red[256][5];
  double loc[5] = {0, 0, 0, 0, 0};
  for (int b = threadIdx.x; b < 2048; b += 256) {
    const double* p = partials + (size_t)b * 5;
    for (int j = 0; j < 5; j++) loc[j] += p[j];
  }
  for (int j = 0; j < 5; j++) red[threadIdx.x][j] = loc[j];
  __syncthreads();
  for (int s = 128; s > 0; s >>= 1) {
    if ((int)threadIdx.x < s)
      for (int j = 0; j < 5; j++) red[threadIdx.x][j] += red[threadIdx.x + s][j];
    __syncthreads();
  }
  if (threadIdx.x == 0) {
    double i0 = red[0][0], i1 = red[0][1], i2 = red[0][2], i3 = red[0][3], l1 = red[0][4];
    double mean = (i0 + i1 + i2 + i3) * 0.25;
    double var = ((i0 - mean) * (i0 - mean) + (i1 - mean) * (i1 - mean) +
                  (i2 - mean) * (i2 - mean) + (i3 - mean) * (i3 - mean)) * 0.25;
    scal[0] = (float)(l1 / (double)NTOK);
    scal[1] = (float)(var / (mean * mean + 1e-10));
    unsigned acc = 0;
    for (int ei = 0; ei < NEXP; ei++) { tileinfo[ei] = acc; acc += (counts[ei] + 63u) >> 6; }
    tileinfo[4] = acc;
  }
}

// ---------------- fused grouped expert FFN ----------------
// LDS map (bytes): Xs [64][512]bf16 @0 (64KB, swz (r&7)<<4)
//                  Hs [64][128]bf16 @65536 (16KB, swz (r&7)<<4)
//                  Wt shared region @81920 (64KB): W1 chunk [128][128] / W2 chunk [512][64], swz (n&7)<<4
//                  idx u32[64] @147456
#define LDS_XS 0
#define LDS_HS 65536
#define LDS_WT 81920
#define LDS_IDX 147456
#define LDS_TOTAL 147712

__global__ __launch_bounds__(512, 1) void ffn_kernel(
    const float* __restrict__ x,
    const float* __restrict__ b1, const float* __restrict__ b2,
    const unsigned short* __restrict__ wb1, const unsigned short* __restrict__ wb2,
    const unsigned* __restrict__ counts, const unsigned* __restrict__ tileinfo,
    const unsigned* __restrict__ perm, const float* __restrict__ gval,
    float* __restrict__ out) {
  extern __shared__ char smem[];
  char* Xs = smem + LDS_XS;
  char* Hs = smem + LDS_HS;
  char* Wt = smem + LDS_WT;
  unsigned* idxs = (unsigned*)(smem + LDS_IDX);

  const unsigned total = tileinfo[4];
  const unsigned bid = blockIdx.x;
  if (bid >= total) return;
  int e = 3;
  while (e > 0 && bid < tileinfo[e]) e--;
  const unsigned trow0 = (bid - tileinfo[e]) * 64u;
  const int mcnt = (int)min(64u, counts[e] - trow0);

  const int tid = threadIdx.x;
  const int lane = tid & 63, wid = tid >> 6;
  const int wm = wid & 1, wn = wid >> 1;

  if (tid < 64) {
    int rr = tid < mcnt ? tid : (mcnt - 1);
    idxs[tid] = perm[(size_t)e * NTOK + trow0 + rr];
  }
  __syncthreads();

  // stage X tile (gather + cvt + swizzled ds_write)
  {
    const int r = tid >> 3, q = tid & 7;
    const float* src = x + (size_t)idxs[r] * DIN;
    const unsigned sw = (unsigned)((r & 7) << 4);
#pragma unroll
    for (int i = 0; i < 8; i++) {
      const int c0 = i * 64 + q * 8;
      float4 f0 = *(const float4*)(src + c0);
      float4 f1 = *(const float4*)(src + c0 + 4);
      short8 v;
      v[0] = (short)f2bf(f0.x); v[1] = (short)f2bf(f0.y);
      v[2] = (short)f2bf(f0.z); v[3] = (short)f2bf(f0.w);
      v[4] = (short)f2bf(f1.x); v[5] = (short)f2bf(f1.y);
      v[6] = (short)f2bf(f1.z); v[7] = (short)f2bf(f1.w);
      *(short8*)(Xs + r * 1024 + ((unsigned)(c0 * 2) ^ sw)) = v;
    }
  }

  f32x4 acc2[2][8];
#pragma unroll
  for (int i = 0; i < 2; i++)
#pragma unroll
    for (int j = 0; j < 8; j++) acc2[i][j] = (f32x4){0.f, 0.f, 0.f, 0.f};

  const unsigned short* w1e = wb1 + (size_t)e * HID * DIN;
  const unsigned short* w2e = wb2 + (size_t)e * DIN * HID;

  for (int hc = 0; hc < 8; hc++) {
    f32x4 acc1[2][2];
#pragma unroll
    for (int i = 0; i < 2; i++)
#pragma unroll
      for (int j = 0; j < 2; j++) acc1[i][j] = (f32x4){0.f, 0.f, 0.f, 0.f};

    // GEMM1: h_chunk[64][128] = X[64][512] * W1[hc*128..][:]^T
    for (int ks = 0; ks < 4; ks++) {
      __syncthreads();  // Wt free (also covers Xs visibility on first iter)
#pragma unroll
      for (int p = 0; p < 4; p++) {  // stage W1 tile [128n][128k] = 32KB
        const unsigned L = (unsigned)(p * 8192 + wid * 1024 + lane * 16);
        const unsigned n = L >> 8, c = L & 255u;
        const unsigned sc = c ^ ((n & 7u) << 4);
        const char* gsrc = (const char*)(w1e + ((size_t)(hc * 128 + (int)n)) * DIN) + ks * 256 + (int)sc;
        __builtin_amdgcn_global_load_lds((gv_t*)gsrc, (lv_t*)(Wt + p * 8192 + wid * 1024), 16, 0, 0);
      }
      asm volatile("s_waitcnt vmcnt(0)" ::: "memory");
      __syncthreads();
#pragma unroll
      for (int s = 0; s < 4; s++) {
        short8 a[2], b[2];
        const int kb = ks * 256 + s * 64 + 16 * (lane >> 4);
#pragma unroll
        for (int mf = 0; mf < 2; mf++) {
          const int r = wm * 32 + mf * 16 + (lane & 15);
          a[mf] = *(const short8*)(Xs + r * 1024 + ((unsigned)kb ^ ((unsigned)(r & 7) << 4)));
        }
        const int cb = s * 64 + 16 * (lane >> 4);
#pragma unroll
        for (int nf = 0; nf < 2; nf++) {
          const int n = wn * 32 + nf * 16 + (lane & 15);
          b[nf] = *(const short8*)(Wt + n * 256 + ((unsigned)cb ^ ((unsigned)(n & 7) << 4)));
        }
#pragma unroll
        for (int mf = 0; mf < 2; mf++)
#pragma unroll
          for (int nf = 0; nf < 2; nf++)
            acc1[mf][nf] = mfma16(a[mf], b[nf], acc1[mf][nf]);
      }
    }

    // bias + relu -> Hs (bf16, swizzled)
#pragma unroll
    for (int mf = 0; mf < 2; mf++)
#pragma unroll
      for (int nf = 0; nf < 2; nf++) {
        const int col = wn * 32 + nf * 16 + (lane & 15);
        const float bias = b1[e * HID + hc * 128 + col];
#pragma unroll
        for (int bb = 0; bb < 4; bb++) {
          const int r = wm * 32 + mf * 16 + 4 * (lane >> 4) + bb;
          float v = acc1[mf][nf][bb] + bias;
          v = v > 0.f ? v : 0.f;
          *(unsigned short*)(Hs + r * 256 + (((unsigned)(col * 2)) ^ ((unsigned)(r & 7) << 4))) = f2bf(v);
        }
      }

    // GEMM2: acc2 += h_chunk[64][128] * W2[:, hc*128..]^T
    for (int ks2 = 0; ks2 < 2; ks2++) {
      __syncthreads();  // Hs written, Wt free
#pragma unroll
      for (int p = 0; p < 8; p++) {  // stage W2 tile [512n][64k] = 64KB
        const unsigned L = (unsigned)(p * 8192 + wid * 1024 + lane * 16);
        const unsigned n = L >> 7, c = L & 127u;
        const unsigned sc = c ^ ((n & 7u) << 4);
        const char* gsrc = (const char*)(w2e + (size_t)n * HID) + hc * 256 + ks2 * 128 + (int)sc;
        __builtin_amdgcn_global_load_lds((gv_t*)gsrc, (lv_t*)(Wt + p * 8192 + wid * 1024), 16, 0, 0);
      }
      asm volatile("s_waitcnt vmcnt(0)" ::: "memory");
      __syncthreads();
#pragma unroll
      for (int s = 0; s < 2; s++) {
        short8 a[2];
        const int kb = ks2 * 128 + s * 64 + 16 * (lane >> 4);
#pragma unroll
        for (int mf = 0; mf < 2; mf++) {
          const int r = wm * 32 + mf * 16 + (lane & 15);
          a[mf] = *(const short8*)(Hs + r * 256 + ((unsigned)kb ^ ((unsigned)(r & 7) << 4)));
        }
        const int cb = s * 64 + 16 * (lane >> 4);
#pragma unroll
        for (int nf = 0; nf < 8; nf++) {
          const int n = wn * 128 + nf * 16 + (lane & 15);
          short8 b = *(const short8*)(Wt + n * 128 + ((unsigned)cb ^ ((unsigned)(n & 7) << 4)));
#pragma unroll
          for (int mf = 0; mf < 2; mf++)
            acc2[mf][nf] = mfma16(a[mf], b, acc2[mf][nf]);
        }
      }
    }
  }

  // epilogue: (y + b2) * gate -> out
#pragma unroll
  for (int mf = 0; mf < 2; mf++)
#pragma unroll
    for (int bb = 0; bb < 4; bb++) {
      const int rt = wm * 32 + mf * 16 + 4 * (lane >> 4) + bb;
      if (rt < mcnt) {
        const unsigned tok = idxs[rt];
        const float g = gval[tok];
        float* orow = out + (size_t)tok * DIN;
#pragma unroll
        for (int nf = 0; nf < 8; nf++) {
          const int col = wn * 128 + nf * 16 + (lane & 15);
          orow[col] = (acc2[mf][nf][bb] + b2[e * DIN + col]) * g;
        }
      }
    }
}

extern "C" void kernel_launch(void* const* d_in, const int* in_sizes, int n_in,
                              void* d_out, int out_size, void* d_ws, size_t ws_size,
                              hipStream_t stream) {
  const float* x   = (const float*)d_in[0];
  const float* emb = (const float*)d_in[1];
  const float* rw  = (const float*)d_in[2];
  const float* w1  = (const float*)d_in[3];
  const float* b1  = (const float*)d_in[4];
  const float* w2  = (const float*)d_in[5];
  const float* b2  = (const float*)d_in[6];
  float* out = (float*)d_out;

  char* ws = (char*)d_ws;
  unsigned* counts = (unsigned*)(ws + OFF_COUNTS);
  unsigned* tileinfo = (unsigned*)(ws + OFF_TILE);
  int* gidx = (int*)(ws + OFF_GIDX);
  float* gval = (float*)(ws + OFF_GVAL);
  unsigned* perm = (unsigned*)(ws + OFF_PERM);
  double* partials = (double*)(ws + OFF_PART);
  unsigned short* wb1 = (unsigned short*)(ws + OFF_WB1);
  unsigned short* wb2 = (unsigned short*)(ws + OFF_WB2);

  hipMemsetAsync(ws, 0, 256, stream);
  cvt_kernel<<<2048, 256, 0, stream>>>((const float4*)w1, (const float4*)w2, wb1, wb2);
  router_kernel<<<2048, 256, 0, stream>>>(x, emb, rw, gidx, gval, partials);
  scatter_kernel<<<128, 256, 0, stream>>>(gidx, counts, perm);
  setup_kernel<<<1, 256, 0, stream>>>(counts, tileinfo, partials, out + 16777216);

  hipFuncSetAttribute((const void*)ffn_kernel, hipFuncAttributeMaxDynamicSharedMemorySize, LDS_TOTAL);
  ffn_kernel<<<516, 512, LDS_TOTAL, stream>>>(x, b1, b2, wb1, wb2, counts, tileinfo, perm, gval, out);
}